// Round 8
// baseline (723.981 us; speedup 1.0000x reference)
//
#include <hip/hip_runtime.h>
#include <hip/hip_fp16.h>
#include <cstddef>

// Problem constants (match reference)
#define N_NODES 100000
#define N_EDGES 1600000
#define E_TOT   (N_EDGES + N_NODES)   // edges + self loops = 1,700,000
#define IN_DIM  64
#define HIDDEN  128
#define Z_DIM   64

// dst-buckets for locality-preserving fill
#define BN 128
#define NB ((N_NODES + BN - 1) / BN)   // 782
#define NBLK 256                        // chunk blocks for binA

using f16x8 = __attribute__((ext_vector_type(8))) _Float16;
using f32x4 = __attribute__((ext_vector_type(4))) float;

// ---------------- prep: x cast + W prep + bucket histogram (one kernel) ----------------
// bhist zeroed by hipMemsetAsync before this kernel.

__global__ __launch_bounds__(256) void prep_k(const float* __restrict__ x, __half* __restrict__ x16,
                                              const float* __restrict__ W1, const float* __restrict__ W2,
                                              const float* __restrict__ Wmu, const float* __restrict__ Wlv,
                                              __half* __restrict__ W1t, __half* __restrict__ W2t,
                                              __half* __restrict__ Wht,
                                              const int* __restrict__ dst, int* __restrict__ bhist) {
    int i = blockIdx.x * 256 + threadIdx.x;
    const int CAST = N_NODES * IN_DIM / 8;        // 800000
    if (i < CAST) {
        const float4* in4 = (const float4*)x;
        float4 a = in4[2 * i], b = in4[2 * i + 1];
        __half2 h0 = __floats2half2_rn(a.x, a.y);
        __half2 h1 = __floats2half2_rn(a.z, a.w);
        __half2 h2 = __floats2half2_rn(b.x, b.y);
        __half2 h3 = __floats2half2_rn(b.z, b.w);
        uint4 pk = make_uint4(*(unsigned*)&h0, *(unsigned*)&h1, *(unsigned*)&h2, *(unsigned*)&h3);
        ((uint4*)x16)[i] = pk;
        return;
    }
    int j = i - CAST;
    if (j < 128 * 64) {
        int col = j >> 6, k = j & 63;
        W1t[j] = __float2half(W1[k * 128 + col]);
        return;
    }
    int m = j - 128 * 64;
    if (m < 128 * 128) {
        int col = m >> 7, k = m & 127;
        W2t[m] = __float2half(W2[k * 128 + col]);
        return;
    }
    int h = m - 128 * 128;
    if (h < 128 * 128) {
        int col = h >> 7, k = h & 127;
        Wht[h] = __float2half(col < 64 ? Wmu[k * 64 + col] : Wlv[k * 64 + (col - 64)]);
        return;
    }
    int z = h - 128 * 128;
    if (z < N_EDGES / 4) {
        int4 d = ((const int4*)dst)[z];
        atomicAdd(&bhist[d.x >> 7], 1);            // fire-and-forget, 782 addrs
        atomicAdd(&bhist[d.y >> 7], 1);
        atomicAdd(&bhist[d.z >> 7], 1);
        atomicAdd(&bhist[d.w >> 7], 1);
    }
}

// single-block exclusive scan of NB bucket counts -> ebase, bcur
__global__ __launch_bounds__(1024) void bscan_k(const int* __restrict__ bhist, int* __restrict__ ebase,
                                                int* __restrict__ bcur, int e) {
    __shared__ int s[1024];
    int t = threadIdx.x;
    int v = (t < NB) ? bhist[t] : 0;
    s[t] = v;
    __syncthreads();
#pragma unroll
    for (int off = 1; off < 1024; off <<= 1) {
        int x = (t >= off) ? s[t - off] : 0;
        __syncthreads();
        s[t] += x;
        __syncthreads();
    }
    if (t < NB) { int ex = s[t] - v; ebase[t] = ex; bcur[t] = ex; }
    if (t == 0) ebase[NB] = e;
}

// Phase A: chunked binning. LDS bucket-hist per block; ONE with-return global atomic per
// (block,bucket) (200K total — no contention stall); place chunk into bucket-contiguous
// binned[] via LDS cursors. Packed 4B: {local_dst(7b) << 17 | src(17b)}.
__global__ __launch_bounds__(256) void binA_k(const int* __restrict__ src, const int* __restrict__ dst,
                                              int* __restrict__ bcur, int* __restrict__ binned, int e) {
    __shared__ int hist[NB];
    __shared__ int cur[NB];
    int t = threadIdx.x;
    int ch = (e + gridDim.x - 1) / gridDim.x;
    int i0 = blockIdx.x * ch;
    int i1 = i0 + ch; if (i1 > e) i1 = e;

    for (int b = t; b < NB; b += 256) hist[b] = 0;
    __syncthreads();
    for (int i = i0 + t; i < i1; i += 256)
        atomicAdd(&hist[dst[i] >> 7], 1);
    __syncthreads();
    for (int b = t; b < NB; b += 256) {
        int h = hist[b];
        cur[b] = h ? atomicAdd(&bcur[b], h) : 0;
    }
    __syncthreads();
    for (int i = i0 + t; i < i1; i += 256) {
        int s = src[i], d = dst[i];
        int p = atomicAdd(&cur[d >> 7], 1);
        binned[p] = ((d & 127) << 17) | s;
    }
}

// Phase B1: one block per bucket — degrees from binned via LDS hist (+1 self), LDS
// 128-scan -> rowptr (em base = ebase[b] + b*BN), dinv = rsqrt(deg). Replaces the
// global count (1.6M cross-XCD atomics) + two 100K-wide scan kernels entirely.
__global__ __launch_bounds__(256) void pdeg_k(const int* __restrict__ binned, const int* __restrict__ ebase,
                                              int* __restrict__ rowptr, float* __restrict__ dinv, int n) {
    __shared__ int hist[BN];
    __shared__ int sc[BN];
    int b = blockIdx.x, t = threadIdx.x;
    int n0 = b * BN;
    int nn = n - n0; if (nn > BN) nn = BN;
    if (t < BN) hist[t] = (t < nn) ? 1 : 0;       // self loop
    __syncthreads();
    int e0 = ebase[b], e1 = ebase[b + 1];
    for (int i = e0 + t; i < e1; i += 256)
        atomicAdd(&hist[binned[i] >> 17], 1);
    __syncthreads();
    int v = (t < BN) ? hist[t] : 0;
    if (t < BN) sc[t] = v;
    __syncthreads();
#pragma unroll
    for (int off = 1; off < BN; off <<= 1) {
        int x = (t < BN && t >= off) ? sc[t - off] : 0;
        __syncthreads();
        if (t < BN) sc[t] += x;
        __syncthreads();
    }
    int base = e0 + n0;                           // global em offset of this bucket
    if (t < nn) {
        rowptr[n0 + t] = base + sc[t] - v;        // exclusive
        dinv[n0 + t] = rsqrtf((float)v);
    }
    if (b == gridDim.x - 1 && t == 0) rowptr[n] = E_TOT;
}

// Phase B2: fill em (dinv now globally complete). Self first, then edges via LDS
// cursors; all writes for the bucket's ~14KB region come from ONE CU -> line-merged.
__global__ __launch_bounds__(256) void pfill_k(const int* __restrict__ binned, const int* __restrict__ ebase,
                                               const int* __restrict__ rowptr, const float* __restrict__ dinv,
                                               int2* __restrict__ em, int n) {
    __shared__ int cur[BN];
    __shared__ float sdv[BN];
    int b = blockIdx.x, t = threadIdx.x;
    int n0 = b * BN;
    int nn = n - n0; if (nn > BN) nn = BN;
    if (t < nn) {
        int rp = rowptr[n0 + t];
        float dv = dinv[n0 + t];
        sdv[t] = dv;
        em[rp] = make_int2(n0 + t, __float_as_int(dv * dv));   // self loop first
        cur[t] = rp + 1;
    }
    __syncthreads();
    int e0 = ebase[b], e1 = ebase[b + 1];
    for (int i = e0 + t; i < e1; i += 256) {
        int pk = binned[i];
        int ld = pk >> 17, s = pk & 0x1FFFF;
        int q = atomicAdd(&cur[ld], 1);
        em[q] = make_int2(s, __float_as_int(dinv[s] * sdv[ld]));
    }
}

// ---------------- Aggregation (gather): fp16 rows, fp32 accumulate ----------------
// One node per wave; granule = 2 slots (STEP edges). 4-phase rotated software pipeline:
// body(p) issues rows(g+2), FMAs granule g, fetches meta(g+4). Prefetches past end are
// clamp-indexed to beg with weight 0 (branch-free). [round-6 structure, measured 66us]

template <int DIM, bool HEAD>
__global__ __launch_bounds__(256) void agg_k(const __half* __restrict__ H, const int* __restrict__ rowptr,
                                             const int2* __restrict__ em, __half* __restrict__ out,
                                             const float* __restrict__ bmu, const float* __restrict__ blv,
                                             float* __restrict__ mu, float* __restrict__ lv, int n) {
    int node = (int)((blockIdx.x * 256 + threadIdx.x) >> 6);
    if (node >= n) return;
    int lane = threadIdx.x & 63;
    int beg = rowptr[node], end = rowptr[node + 1];
    const uint4* H4 = (const uint4*)H;

    constexpr int RV   = DIM / 8;            // 16B-chunks per row (128->16, 64->8)
    constexpr int SUBS = 64 / RV;            // parallel edge slots (4 or 8)
    constexpr int STEP = SUBS * 2;           // edges per granule (8 or 16)
    int sub = lane / RV;
    int fl  = lane % RV;

    float acc[8];
#pragma unroll
    for (int q = 0; q < 8; q++) acc[q] = 0.f;

    auto meta = [&](int j, int p, int& s, float& w) {
        int idx = j + SUBS * p + sub;
        int ci  = idx < end ? idx : beg;
        int2 e  = em[ci];
        s = e.x;
        w = idx < end ? __int_as_float(e.y) : 0.f;
    };
    auto rows = [&](int s0, int s1, uint4& r0, uint4& r1) {
        r0 = H4[(size_t)s0 * RV + fl];
        r1 = H4[(size_t)s1 * RV + fl];
    };
    auto fmas = [&](const uint4& r0, const uint4& r1, float ww0, float ww1) {
        const __half* h0 = (const __half*)&r0;
        const __half* h1 = (const __half*)&r1;
#pragma unroll
        for (int q = 0; q < 8; q++) acc[q] = fmaf(ww0, __half2float(h0[q]), acc[q]);
#pragma unroll
        for (int q = 0; q < 8; q++) acc[q] = fmaf(ww1, __half2float(h1[q]), acc[q]);
    };

    int G = (end - beg + STEP - 1) / STEP;   // granules (>=1: self loop)

    int   sa0, sa1, sb0, sb1, sc0, sc1, sd0, sd1;
    float wa0, wa1, wb0, wb1, wc0, wc1, wd0, wd1;
    uint4 ra0, ra1, rb0, rb1, rc0, rc1, rd0, rd1;

    // prologue: meta g0..g3, rows g0,g1
    meta(beg,            0, sa0, wa0); meta(beg,            1, sa1, wa1);
    meta(beg + STEP,     0, sb0, wb0); meta(beg + STEP,     1, sb1, wb1);
    rows(sa0, sa1, ra0, ra1);
    rows(sb0, sb1, rb0, rb1);
    meta(beg + 2 * STEP, 0, sc0, wc0); meta(beg + 2 * STEP, 1, sc1, wc1);
    meta(beg + 3 * STEP, 0, sd0, wd0); meta(beg + 3 * STEP, 1, sd1, wd1);

    int g = 0;
    int jf = beg + 4 * STEP;                 // next meta granule start to fetch
    while (true) {
        rows(sc0, sc1, rc0, rc1);            // issue g+2
        fmas(ra0, ra1, wa0, wa1);            // consume g
        if (++g >= G) break;
        meta(jf, 0, sa0, wa0); meta(jf, 1, sa1, wa1); jf += STEP;   // fetch g+4

        rows(sd0, sd1, rd0, rd1);
        fmas(rb0, rb1, wb0, wb1);
        if (++g >= G) break;
        meta(jf, 0, sb0, wb0); meta(jf, 1, sb1, wb1); jf += STEP;

        rows(sa0, sa1, ra0, ra1);
        fmas(rc0, rc1, wc0, wc1);
        if (++g >= G) break;
        meta(jf, 0, sc0, wc0); meta(jf, 1, sc1, wc1); jf += STEP;

        rows(sb0, sb1, rb0, rb1);
        fmas(rd0, rd1, wd0, wd1);
        if (++g >= G) break;
        meta(jf, 0, sd0, wd0); meta(jf, 1, sd1, wd1); jf += STEP;
    }

    // combine sub-groups: xor-reduce down to sub==0
#pragma unroll
    for (int off = 32; off >= RV; off >>= 1) {
#pragma unroll
        for (int q = 0; q < 8; q++) acc[q] += __shfl_xor(acc[q], off);
    }
    if (sub == 0) {
        if constexpr (HEAD) {
            // feats fl*8 .. fl*8+7; fl<8 -> mu, fl>=8 -> logvar (chunks don't straddle 64)
            const float* bp = (fl < 8) ? (bmu + fl * 8) : (blv + (fl - 8) * 8);
#pragma unroll
            for (int q = 0; q < 8; q++) acc[q] += bp[q];
            float* op = (fl < 8) ? (mu + (size_t)node * 64 + fl * 8)
                                 : (lv + (size_t)node * 64 + (fl - 8) * 8);
            *(float4*)op = make_float4(acc[0], acc[1], acc[2], acc[3]);
            *(float4*)(op + 4) = make_float4(acc[4], acc[5], acc[6], acc[7]);
        } else {
            __half2 q0 = __floats2half2_rn(acc[0], acc[1]);
            __half2 q1 = __floats2half2_rn(acc[2], acc[3]);
            __half2 q2 = __floats2half2_rn(acc[4], acc[5]);
            __half2 q3 = __floats2half2_rn(acc[6], acc[7]);
            uint4 pk = make_uint4(*(unsigned*)&q0, *(unsigned*)&q1, *(unsigned*)&q2, *(unsigned*)&q3);
            *(uint4*)(out + (size_t)node * DIM + fl * 8) = pk;
        }
    }
}

// ---------------- MFMA GEMM: C[n x 128] = A[n x K] @ W[K x 128] (+bias, relu) ----------
// 256 thr = 4 waves, 64 rows/block (wave w -> rows m0+16w..+15), 8 col-tiles per wave.
// W^T fp16 staged in LDS ([col][k], 16/32 KB) with XOR swizzle ^((col&7)<<4) to kill the
// 16-way ds_read_b128 bank conflict. A fragments loaded direct from global (16B/lane).
// mfma_f32_16x16x32_f16: a[e]=A[lane&15][(lane>>4)*8+e], b[e]=W[(lane>>4)*8+e][col],
// d[r]=C[(lane>>4)*4+r][col=lane&15] (per verified gfx950 layout).

template <int K, bool BR>
__global__ __launch_bounds__(256) void mgemm_k(const __half* __restrict__ A,
                                               const __half* __restrict__ Wt,   // [128][K] fp16
                                               const float* __restrict__ bias,
                                               __half* __restrict__ C, int n) {
    __shared__ __align__(16) __half Wl[128 * K];
    int t = threadIdx.x;

    // stage Wt -> LDS (16B chunks, XOR swizzle on write; reads use the same XOR)
    constexpr int CHUNKS = 128 * K / 8;     // 16B chunks
    const uint4* Wg = (const uint4*)Wt;
    for (int i = t; i < CHUNKS; i += 256) {
        int g = i * 16;
        int col = g / (2 * K);
        uint4 v = Wg[i];
        *(uint4*)((char*)Wl + (g ^ ((col & 7) << 4))) = v;
    }
    __syncthreads();

    int lane = t & 63, w = t >> 6;
    int colb = lane & 15;
    int kq = (lane >> 4) * 8;
    int m0 = blockIdx.x * 64 + w * 16;
    int rowA = m0 + colb; if (rowA >= n) rowA = n - 1;
    const __half* Arow = A + (size_t)rowA * K + kq;

    f32x4 acc[8];
#pragma unroll
    for (int c = 0; c < 8; c++) acc[c] = (f32x4){0.f, 0.f, 0.f, 0.f};

    const char* wb = (const char*)Wl;
    int swz = (colb & 7) << 4;
    int off0 = colb * (2 * K) + kq * 2;

#pragma unroll
    for (int k0 = 0; k0 < K; k0 += 32) {
        f16x8 a = *(const f16x8*)(Arow + k0);
#pragma unroll
        for (int c = 0; c < 8; c++) {
            f16x8 b = *(const f16x8*)(wb + ((off0 + c * (32 * K) + k0 * 2) ^ swz));
            acc[c] = __builtin_amdgcn_mfma_f32_16x16x32_f16(a, b, acc[c], 0, 0, 0);
        }
    }

    int rbase = m0 + (lane >> 4) * 4;
#pragma unroll
    for (int c = 0; c < 8; c++) {
        int col = c * 16 + colb;
        float bv = BR ? bias[col] : 0.f;
#pragma unroll
        for (int r = 0; r < 4; r++) {
            int row = rbase + r;
            if (row < n) {
                float v = acc[c][r] + bv;
                if (BR) v = fmaxf(v, 0.f);
                C[(size_t)row * 128 + col] = __float2half(v);
            }
        }
    }
}

// ---------------- launch ----------------

extern "C" void kernel_launch(void* const* d_in, const int* in_sizes, int n_in,
                              void* d_out, int out_size, void* d_ws, size_t ws_size,
                              hipStream_t stream) {
    const int N = N_NODES, E = N_EDGES, ETOT = E_TOT;

    const float* x    = (const float*)d_in[0];
    const int*   ei   = (const int*)d_in[1];
    const int*   srcA = ei;
    const int*   dstA = ei + E;
    const float* W1   = (const float*)d_in[2];
    const float* b1   = (const float*)d_in[3];
    const float* W2   = (const float*)d_in[4];
    const float* b2   = (const float*)d_in[5];
    const float* Wmu  = (const float*)d_in[6];
    const float* bmu  = (const float*)d_in[7];
    const float* Wlv  = (const float*)d_in[8];
    const float* blv  = (const float*)d_in[9];
    float* out = (float*)d_out;

    // workspace carve-out
    char* ws = (char*)d_ws;
    size_t o = 0;
    auto alloc = [&](size_t bytes) -> void* {
        o = (o + 255) & ~(size_t)255;
        void* p = ws + o;
        o += bytes;
        return p;
    };
    int*    bhist  = (int*)alloc((size_t)(NB + 1) * 4);
    int*    ebase  = (int*)alloc((size_t)(NB + 1) * 4);
    int*    bcur   = (int*)alloc((size_t)(NB + 1) * 4);
    int*    rowptr = (int*)alloc((size_t)(N + 1) * 4);
    float*  dinv   = (float*)alloc((size_t)N * 4);
    int2*   em     = (int2*)alloc((size_t)ETOT * 8);          // packed {src, norm}
    int*    binned = (int*)alloc((size_t)E * 4);
    __half* x16    = (__half*)alloc((size_t)N * IN_DIM * 2);
    __half* B1     = (__half*)alloc((size_t)N * HIDDEN * 2);  // agg out / P
    __half* B2     = (__half*)alloc((size_t)N * HIDDEN * 2);  // gemm out
    __half* W1t    = (__half*)alloc(128 * 64 * 2);
    __half* W2t    = (__half*)alloc(128 * 128 * 2);
    __half* Wht    = (__half*)alloc(128 * 128 * 2);
    (void)ws_size;

    const int PREP_T = N * IN_DIM / 8 + 128 * 64 + 128 * 128 + 128 * 128 + E / 4;
    const int gPrep = (PREP_T + 255) / 256;
    const int gAgg = (N + 3) / 4;            // 25000 (4 nodes/block)
    const int gMg  = (N + 63) / 64;          // 1563 (64 rows/block)

    // CSR build: bucket histogram (in prep) -> 1-block scan -> chunked bin ->
    // bucket-local degree+scan -> bucket-local fill. No global count, no 100K scans.
    hipMemsetAsync(bhist, 0, (size_t)NB * 4, stream);
    prep_k<<<gPrep, 256, 0, stream>>>(x, x16, W1, W2, Wmu, Wlv, W1t, W2t, Wht, dstA, bhist);
    bscan_k<<<1, 1024, 0, stream>>>(bhist, ebase, bcur, E);
    binA_k<<<NBLK, 256, 0, stream>>>(srcA, dstA, bcur, binned, E);
    pdeg_k<<<NB, 256, 0, stream>>>(binned, ebase, rowptr, dinv, N);
    pfill_k<<<NB, 256, 0, stream>>>(binned, ebase, rowptr, dinv, em, N);

    // layer 1: h = relu(Agg(x16) @ W1 + b1)        [agg 64-dim -> MFMA K=64]
    agg_k<64, false><<<gAgg, 256, 0, stream>>>(x16, rowptr, em, B1, nullptr, nullptr, nullptr, nullptr, N);
    mgemm_k<64, true><<<gMg, 256, 0, stream>>>(B1, W1t, b1, B2, N);

    // layer 2: h = relu(Agg(h) @ W2 + b2)          [agg 128-dim -> MFMA K=128]
    agg_k<128, false><<<gAgg, 256, 0, stream>>>(B2, rowptr, em, B1, nullptr, nullptr, nullptr, nullptr, N);
    mgemm_k<128, true><<<gMg, 256, 0, stream>>>(B1, W2t, b2, B2, N);

    // heads via linearity: P = h @ [Wmu|Wlv] (fp16), then out = Agg(P) + bias (fp32)
    mgemm_k<128, false><<<gMg, 256, 0, stream>>>(B2, Wht, nullptr, B1, N);
    agg_k<128, true><<<gAgg, 256, 0, stream>>>(B1, rowptr, em, nullptr, bmu, blv,
                                               out, out + (size_t)N * Z_DIM, N);
}

// Round 9
// 369.806 us; speedup vs baseline: 1.9577x; 1.9577x over previous
//
#include <hip/hip_runtime.h>
#include <hip/hip_fp16.h>
#include <cstddef>

// Problem constants (match reference)
#define N_NODES 100000
#define N_EDGES 1600000
#define E_TOT   (N_EDGES + N_NODES)   // edges + self loops = 1,700,000
#define IN_DIM  64
#define HIDDEN  128
#define Z_DIM   64

// dst-buckets for locality-preserving fill
#define BN 128
#define NB ((N_NODES + BN - 1) / BN)   // 782
#define NCH 128                         // chunk blocks for hist/bin (no global atomics)

using f16x8 = __attribute__((ext_vector_type(8))) _Float16;
using f32x4 = __attribute__((ext_vector_type(4))) float;

// ---------------- prep: x cast + W prep (one kernel) ----------------

__global__ __launch_bounds__(256) void prep_k(const float* __restrict__ x, __half* __restrict__ x16,
                                              const float* __restrict__ W1, const float* __restrict__ W2,
                                              const float* __restrict__ Wmu, const float* __restrict__ Wlv,
                                              __half* __restrict__ W1t, __half* __restrict__ W2t,
                                              __half* __restrict__ Wht) {
    int i = blockIdx.x * 256 + threadIdx.x;
    const int CAST = N_NODES * IN_DIM / 8;        // 800000
    if (i < CAST) {
        const float4* in4 = (const float4*)x;
        float4 a = in4[2 * i], b = in4[2 * i + 1];
        __half2 h0 = __floats2half2_rn(a.x, a.y);
        __half2 h1 = __floats2half2_rn(a.z, a.w);
        __half2 h2 = __floats2half2_rn(b.x, b.y);
        __half2 h3 = __floats2half2_rn(b.z, b.w);
        uint4 pk = make_uint4(*(unsigned*)&h0, *(unsigned*)&h1, *(unsigned*)&h2, *(unsigned*)&h3);
        ((uint4*)x16)[i] = pk;
        return;
    }
    int j = i - CAST;
    if (j < 128 * 64) {
        int col = j >> 6, k = j & 63;
        W1t[j] = __float2half(W1[k * 128 + col]);
        return;
    }
    int m = j - 128 * 64;
    if (m < 128 * 128) {
        int col = m >> 7, k = m & 127;
        W2t[m] = __float2half(W2[k * 128 + col]);
        return;
    }
    int h = m - 128 * 128;
    if (h < 128 * 128) {
        int col = h >> 7, k = h & 127;
        Wht[h] = __float2half(col < 64 ? Wmu[k * 64 + col] : Wlv[k * 64 + (col - 64)]);
    }
}

// ---------------- CSR build: atomic-free two-pass counting sort ----------------
// Lesson (r1/r8): same-address global atomics serialize at ~440cy/update regardless of
// return semantics — 1.6M updates on 782 addrs = ~380us. All global atomics eliminated.

// Pass 1: per-chunk LDS bucket histogram -> histG[c][b] (coalesced store, no global atomics)
__global__ __launch_bounds__(256) void hist_k(const int* __restrict__ dst, int* __restrict__ histG, int e) {
    __shared__ int hist[NB];
    int c = blockIdx.x, t = threadIdx.x;
    int ch = (e + NCH - 1) / NCH;
    int i0 = c * ch, i1 = i0 + ch; if (i1 > e) i1 = e;
    for (int b = t; b < NB; b += 256) hist[b] = 0;
    __syncthreads();
    for (int i = i0 + t; i < i1; i += 256)
        atomicAdd(&hist[dst[i] >> 7], 1);      // LDS atomics, ~16/counter
    __syncthreads();
    for (int b = t; b < NB; b += 256) histG[c * NB + b] = hist[b];
}

// Pass 2 (1 block): per-bucket running prefix over chunks -> boffs[c][b] (chunk-local
// start inside bucket), bucket totals -> LDS scan -> ebase. ~1.6MB r/w, L2-resident.
__global__ __launch_bounds__(1024) void boff_k(int* __restrict__ histG /*in: counts, out: boffs*/,
                                               int* __restrict__ ebase, int e) {
    __shared__ int s[1024];
    int t = threadIdx.x;
    int run = 0;
    if (t < NB) {
        for (int c = 0; c < NCH; c++) {
            int v = histG[c * NB + t];
            histG[c * NB + t] = run;           // local prefix within bucket
            run += v;
        }
    }
    s[t] = (t < NB) ? run : 0;
    __syncthreads();
#pragma unroll
    for (int off = 1; off < 1024; off <<= 1) {
        int x = (t >= off) ? s[t - off] : 0;
        __syncthreads();
        s[t] += x;
        __syncthreads();
    }
    if (t < NB) ebase[t] = s[t] - run;         // exclusive
    if (t == 0) ebase[NB] = e;
}

// Pass 3: place edges into bucket-contiguous binned[] via LDS cursors seeded from
// ebase[b] + boffs[c][b]. NO global atomics. Packed 4B: {local_dst(7b)<<17 | src(17b)}.
__global__ __launch_bounds__(256) void binB_k(const int* __restrict__ src, const int* __restrict__ dst,
                                              const int* __restrict__ boffs, const int* __restrict__ ebase,
                                              int* __restrict__ binned, int e) {
    __shared__ int cur[NB];
    int c = blockIdx.x, t = threadIdx.x;
    int ch = (e + NCH - 1) / NCH;
    int i0 = c * ch, i1 = i0 + ch; if (i1 > e) i1 = e;
    for (int b = t; b < NB; b += 256) cur[b] = ebase[b] + boffs[c * NB + b];
    __syncthreads();
    for (int i = i0 + t; i < i1; i += 256) {
        int s = src[i], d = dst[i];
        int p = atomicAdd(&cur[d >> 7], 1);    // LDS atomic
        binned[p] = ((d & 127) << 17) | s;
    }
}

// Phase B1: one block per bucket — degrees from binned via LDS hist (+1 self), LDS
// 128-scan -> rowptr (em base = ebase[b] + b*BN), dinv = rsqrt(deg).
__global__ __launch_bounds__(256) void pdeg_k(const int* __restrict__ binned, const int* __restrict__ ebase,
                                              int* __restrict__ rowptr, float* __restrict__ dinv, int n) {
    __shared__ int hist[BN];
    __shared__ int sc[BN];
    int b = blockIdx.x, t = threadIdx.x;
    int n0 = b * BN;
    int nn = n - n0; if (nn > BN) nn = BN;
    if (t < BN) hist[t] = (t < nn) ? 1 : 0;    // self loop
    __syncthreads();
    int e0 = ebase[b], e1 = ebase[b + 1];
    for (int i = e0 + t; i < e1; i += 256)
        atomicAdd(&hist[binned[i] >> 17], 1);
    __syncthreads();
    int v = (t < BN) ? hist[t] : 0;
    if (t < BN) sc[t] = v;
    __syncthreads();
#pragma unroll
    for (int off = 1; off < BN; off <<= 1) {
        int x = (t < BN && t >= off) ? sc[t - off] : 0;
        __syncthreads();
        if (t < BN) sc[t] += x;
        __syncthreads();
    }
    int base = e0 + n0;                        // global em offset of this bucket
    if (t < nn) {
        rowptr[n0 + t] = base + sc[t] - v;     // exclusive
        dinv[n0 + t] = rsqrtf((float)v);
    }
    if (b == gridDim.x - 1 && t == 0) rowptr[n] = E_TOT;
}

// Phase B2: fill em (dinv globally complete). Self first, then edges via LDS cursors;
// all writes for the bucket's ~14KB region come from ONE CU -> line-merged in its L2.
__global__ __launch_bounds__(256) void pfill_k(const int* __restrict__ binned, const int* __restrict__ ebase,
                                               const int* __restrict__ rowptr, const float* __restrict__ dinv,
                                               int2* __restrict__ em, int n) {
    __shared__ int cur[BN];
    __shared__ float sdv[BN];
    int b = blockIdx.x, t = threadIdx.x;
    int n0 = b * BN;
    int nn = n - n0; if (nn > BN) nn = BN;
    if (t < nn) {
        int rp = rowptr[n0 + t];
        float dv = dinv[n0 + t];
        sdv[t] = dv;
        em[rp] = make_int2(n0 + t, __float_as_int(dv * dv));   // self loop first
        cur[t] = rp + 1;
    }
    __syncthreads();
    int e0 = ebase[b], e1 = ebase[b + 1];
    for (int i = e0 + t; i < e1; i += 256) {
        int pk = binned[i];
        int ld = pk >> 17, s = pk & 0x1FFFF;
        int q = atomicAdd(&cur[ld], 1);
        em[q] = make_int2(s, __float_as_int(dinv[s] * sdv[ld]));
    }
}

// ---------------- Aggregation (gather): fp16 rows, fp32 accumulate ----------------
// One node per wave; granule = 2 slots (STEP edges). 4-phase rotated software pipeline:
// body(p) issues rows(g+2), FMAs granule g, fetches meta(g+4). Prefetches past end are
// clamp-indexed to beg with weight 0 (branch-free). [round-6 structure, measured 66us]

template <int DIM, bool HEAD>
__global__ __launch_bounds__(256) void agg_k(const __half* __restrict__ H, const int* __restrict__ rowptr,
                                             const int2* __restrict__ em, __half* __restrict__ out,
                                             const float* __restrict__ bmu, const float* __restrict__ blv,
                                             float* __restrict__ mu, float* __restrict__ lv, int n) {
    int node = (int)((blockIdx.x * 256 + threadIdx.x) >> 6);
    if (node >= n) return;
    int lane = threadIdx.x & 63;
    int beg = rowptr[node], end = rowptr[node + 1];
    const uint4* H4 = (const uint4*)H;

    constexpr int RV   = DIM / 8;            // 16B-chunks per row (128->16, 64->8)
    constexpr int SUBS = 64 / RV;            // parallel edge slots (4 or 8)
    constexpr int STEP = SUBS * 2;           // edges per granule (8 or 16)
    int sub = lane / RV;
    int fl  = lane % RV;

    float acc[8];
#pragma unroll
    for (int q = 0; q < 8; q++) acc[q] = 0.f;

    auto meta = [&](int j, int p, int& s, float& w) {
        int idx = j + SUBS * p + sub;
        int ci  = idx < end ? idx : beg;
        int2 e  = em[ci];
        s = e.x;
        w = idx < end ? __int_as_float(e.y) : 0.f;
    };
    auto rows = [&](int s0, int s1, uint4& r0, uint4& r1) {
        r0 = H4[(size_t)s0 * RV + fl];
        r1 = H4[(size_t)s1 * RV + fl];
    };
    auto fmas = [&](const uint4& r0, const uint4& r1, float ww0, float ww1) {
        const __half* h0 = (const __half*)&r0;
        const __half* h1 = (const __half*)&r1;
#pragma unroll
        for (int q = 0; q < 8; q++) acc[q] = fmaf(ww0, __half2float(h0[q]), acc[q]);
#pragma unroll
        for (int q = 0; q < 8; q++) acc[q] = fmaf(ww1, __half2float(h1[q]), acc[q]);
    };

    int G = (end - beg + STEP - 1) / STEP;   // granules (>=1: self loop)

    int   sa0, sa1, sb0, sb1, sc0, sc1, sd0, sd1;
    float wa0, wa1, wb0, wb1, wc0, wc1, wd0, wd1;
    uint4 ra0, ra1, rb0, rb1, rc0, rc1, rd0, rd1;

    // prologue: meta g0..g3, rows g0,g1
    meta(beg,            0, sa0, wa0); meta(beg,            1, sa1, wa1);
    meta(beg + STEP,     0, sb0, wb0); meta(beg + STEP,     1, sb1, wb1);
    rows(sa0, sa1, ra0, ra1);
    rows(sb0, sb1, rb0, rb1);
    meta(beg + 2 * STEP, 0, sc0, wc0); meta(beg + 2 * STEP, 1, sc1, wc1);
    meta(beg + 3 * STEP, 0, sd0, wd0); meta(beg + 3 * STEP, 1, sd1, wd1);

    int g = 0;
    int jf = beg + 4 * STEP;                 // next meta granule start to fetch
    while (true) {
        rows(sc0, sc1, rc0, rc1);            // issue g+2
        fmas(ra0, ra1, wa0, wa1);            // consume g
        if (++g >= G) break;
        meta(jf, 0, sa0, wa0); meta(jf, 1, sa1, wa1); jf += STEP;   // fetch g+4

        rows(sd0, sd1, rd0, rd1);
        fmas(rb0, rb1, wb0, wb1);
        if (++g >= G) break;
        meta(jf, 0, sb0, wb0); meta(jf, 1, sb1, wb1); jf += STEP;

        rows(sa0, sa1, ra0, ra1);
        fmas(rc0, rc1, wc0, wc1);
        if (++g >= G) break;
        meta(jf, 0, sc0, wc0); meta(jf, 1, sc1, wc1); jf += STEP;

        rows(sb0, sb1, rb0, rb1);
        fmas(rd0, rd1, wd0, wd1);
        if (++g >= G) break;
        meta(jf, 0, sd0, wd0); meta(jf, 1, sd1, wd1); jf += STEP;
    }

    // combine sub-groups: xor-reduce down to sub==0
#pragma unroll
    for (int off = 32; off >= RV; off >>= 1) {
#pragma unroll
        for (int q = 0; q < 8; q++) acc[q] += __shfl_xor(acc[q], off);
    }
    if (sub == 0) {
        if constexpr (HEAD) {
            // feats fl*8 .. fl*8+7; fl<8 -> mu, fl>=8 -> logvar (chunks don't straddle 64)
            const float* bp = (fl < 8) ? (bmu + fl * 8) : (blv + (fl - 8) * 8);
#pragma unroll
            for (int q = 0; q < 8; q++) acc[q] += bp[q];
            float* op = (fl < 8) ? (mu + (size_t)node * 64 + fl * 8)
                                 : (lv + (size_t)node * 64 + (fl - 8) * 8);
            *(float4*)op = make_float4(acc[0], acc[1], acc[2], acc[3]);
            *(float4*)(op + 4) = make_float4(acc[4], acc[5], acc[6], acc[7]);
        } else {
            __half2 q0 = __floats2half2_rn(acc[0], acc[1]);
            __half2 q1 = __floats2half2_rn(acc[2], acc[3]);
            __half2 q2 = __floats2half2_rn(acc[4], acc[5]);
            __half2 q3 = __floats2half2_rn(acc[6], acc[7]);
            uint4 pk = make_uint4(*(unsigned*)&q0, *(unsigned*)&q1, *(unsigned*)&q2, *(unsigned*)&q3);
            *(uint4*)(out + (size_t)node * DIM + fl * 8) = pk;
        }
    }
}

// ---------------- MFMA GEMM: C[n x 128] = A[n x K] @ W[K x 128] (+bias, relu) ----------
// 256 thr = 4 waves, 64 rows/block (wave w -> rows m0+16w..+15), 8 col-tiles per wave.
// W^T fp16 staged in LDS ([col][k], 16/32 KB) with XOR swizzle ^((col&7)<<4) to kill the
// 16-way ds_read_b128 bank conflict. A fragments loaded direct from global (16B/lane).
// mfma_f32_16x16x32_f16: a[e]=A[lane&15][(lane>>4)*8+e], b[e]=W[(lane>>4)*8+e][col],
// d[r]=C[(lane>>4)*4+r][col=lane&15] (per verified gfx950 layout).

template <int K, bool BR>
__global__ __launch_bounds__(256) void mgemm_k(const __half* __restrict__ A,
                                               const __half* __restrict__ Wt,   // [128][K] fp16
                                               const float* __restrict__ bias,
                                               __half* __restrict__ C, int n) {
    __shared__ __align__(16) __half Wl[128 * K];
    int t = threadIdx.x;

    // stage Wt -> LDS (16B chunks, XOR swizzle on write; reads use the same XOR)
    constexpr int CHUNKS = 128 * K / 8;     // 16B chunks
    const uint4* Wg = (const uint4*)Wt;
    for (int i = t; i < CHUNKS; i += 256) {
        int g = i * 16;
        int col = g / (2 * K);
        uint4 v = Wg[i];
        *(uint4*)((char*)Wl + (g ^ ((col & 7) << 4))) = v;
    }
    __syncthreads();

    int lane = t & 63, w = t >> 6;
    int colb = lane & 15;
    int kq = (lane >> 4) * 8;
    int m0 = blockIdx.x * 64 + w * 16;
    int rowA = m0 + colb; if (rowA >= n) rowA = n - 1;
    const __half* Arow = A + (size_t)rowA * K + kq;

    f32x4 acc[8];
#pragma unroll
    for (int c = 0; c < 8; c++) acc[c] = (f32x4){0.f, 0.f, 0.f, 0.f};

    const char* wb = (const char*)Wl;
    int swz = (colb & 7) << 4;
    int off0 = colb * (2 * K) + kq * 2;

#pragma unroll
    for (int k0 = 0; k0 < K; k0 += 32) {
        f16x8 a = *(const f16x8*)(Arow + k0);
#pragma unroll
        for (int c = 0; c < 8; c++) {
            f16x8 b = *(const f16x8*)(wb + ((off0 + c * (32 * K) + k0 * 2) ^ swz));
            acc[c] = __builtin_amdgcn_mfma_f32_16x16x32_f16(a, b, acc[c], 0, 0, 0);
        }
    }

    int rbase = m0 + (lane >> 4) * 4;
#pragma unroll
    for (int c = 0; c < 8; c++) {
        int col = c * 16 + colb;
        float bv = BR ? bias[col] : 0.f;
#pragma unroll
        for (int r = 0; r < 4; r++) {
            int row = rbase + r;
            if (row < n) {
                float v = acc[c][r] + bv;
                if (BR) v = fmaxf(v, 0.f);
                C[(size_t)row * 128 + col] = __float2half(v);
            }
        }
    }
}

// ---------------- launch ----------------

extern "C" void kernel_launch(void* const* d_in, const int* in_sizes, int n_in,
                              void* d_out, int out_size, void* d_ws, size_t ws_size,
                              hipStream_t stream) {
    const int N = N_NODES, E = N_EDGES, ETOT = E_TOT;

    const float* x    = (const float*)d_in[0];
    const int*   ei   = (const int*)d_in[1];
    const int*   srcA = ei;
    const int*   dstA = ei + E;
    const float* W1   = (const float*)d_in[2];
    const float* b1   = (const float*)d_in[3];
    const float* W2   = (const float*)d_in[4];
    const float* b2   = (const float*)d_in[5];
    const float* Wmu  = (const float*)d_in[6];
    const float* bmu  = (const float*)d_in[7];
    const float* Wlv  = (const float*)d_in[8];
    const float* blv  = (const float*)d_in[9];
    float* out = (float*)d_out;

    // workspace carve-out
    char* ws = (char*)d_ws;
    size_t o = 0;
    auto alloc = [&](size_t bytes) -> void* {
        o = (o + 255) & ~(size_t)255;
        void* p = ws + o;
        o += bytes;
        return p;
    };
    int*    histG  = (int*)alloc((size_t)NCH * NB * 4);       // counts -> boffs (in place)
    int*    ebase  = (int*)alloc((size_t)(NB + 1) * 4);
    int*    rowptr = (int*)alloc((size_t)(N + 1) * 4);
    float*  dinv   = (float*)alloc((size_t)N * 4);
    int2*   em     = (int2*)alloc((size_t)ETOT * 8);          // packed {src, norm}
    int*    binned = (int*)alloc((size_t)E * 4);
    __half* x16    = (__half*)alloc((size_t)N * IN_DIM * 2);
    __half* B1     = (__half*)alloc((size_t)N * HIDDEN * 2);  // agg out / P
    __half* B2     = (__half*)alloc((size_t)N * HIDDEN * 2);  // gemm out
    __half* W1t    = (__half*)alloc(128 * 64 * 2);
    __half* W2t    = (__half*)alloc(128 * 128 * 2);
    __half* Wht    = (__half*)alloc(128 * 128 * 2);
    (void)ws_size;

    const int PREP_T = N * IN_DIM / 8 + 128 * 64 + 128 * 128 + 128 * 128;
    const int gPrep = (PREP_T + 255) / 256;
    const int gAgg = (N + 3) / 4;            // 25000 (4 nodes/block)
    const int gMg  = (N + 63) / 64;          // 1563 (64 rows/block)

    // CSR build, fully atomic-free at global scope:
    // chunk-hist -> 1-block chunk-prefix+bucket-scan -> chunk-place -> bucket-local
    // degree+scan -> bucket-local fill.
    prep_k<<<gPrep, 256, 0, stream>>>(x, x16, W1, W2, Wmu, Wlv, W1t, W2t, Wht);
    hist_k<<<NCH, 256, 0, stream>>>(dstA, histG, E);
    boff_k<<<1, 1024, 0, stream>>>(histG, ebase, E);
    binB_k<<<NCH, 256, 0, stream>>>(srcA, dstA, histG, ebase, binned, E);
    pdeg_k<<<NB, 256, 0, stream>>>(binned, ebase, rowptr, dinv, N);
    pfill_k<<<NB, 256, 0, stream>>>(binned, ebase, rowptr, dinv, em, N);

    // layer 1: h = relu(Agg(x16) @ W1 + b1)        [agg 64-dim -> MFMA K=64]
    agg_k<64, false><<<gAgg, 256, 0, stream>>>(x16, rowptr, em, B1, nullptr, nullptr, nullptr, nullptr, N);
    mgemm_k<64, true><<<gMg, 256, 0, stream>>>(B1, W1t, b1, B2, N);

    // layer 2: h = relu(Agg(h) @ W2 + b2)          [agg 128-dim -> MFMA K=128]
    agg_k<128, false><<<gAgg, 256, 0, stream>>>(B2, rowptr, em, B1, nullptr, nullptr, nullptr, nullptr, N);
    mgemm_k<128, true><<<gMg, 256, 0, stream>>>(B1, W2t, b2, B2, N);

    // heads via linearity: P = h @ [Wmu|Wlv] (fp16), then out = Agg(P) + bias (fp32)
    mgemm_k<128, false><<<gMg, 256, 0, stream>>>(B2, Wht, nullptr, B1, N);
    agg_k<128, true><<<gAgg, 256, 0, stream>>>(B1, rowptr, em, nullptr, bmu, blv,
                                               out, out + (size_t)N * Z_DIM, N);
}

// Round 11
// 359.681 us; speedup vs baseline: 2.0128x; 1.0282x over previous
//
#include <hip/hip_runtime.h>
#include <hip/hip_fp16.h>
#include <cstddef>

// Problem constants (match reference)
#define N_NODES 100000
#define N_EDGES 1600000
#define E_TOT   (N_EDGES + N_NODES)   // edges + self loops = 1,700,000
#define IN_DIM  64
#define HIDDEN  128
#define Z_DIM   64

// dst-buckets for locality-preserving fill
#define BN 128
#define NB ((N_NODES + BN - 1) / BN)   // 782
#define NCH 256                         // chunk blocks for hist/bin (no global atomics)

using f16x8 = __attribute__((ext_vector_type(8))) _Float16;
using f32x4 = __attribute__((ext_vector_type(4))) float;

// ---------------- prep: x cast + W prep + chunk bucket-histogram (one kernel) ----------
// Blocks [0, nPrep): cast/W-prep streaming. Blocks [nPrep, nPrep+NCH): per-chunk LDS
// bucket histogram of dst -> histG[c][b] (no global atomics; overlaps the streaming).

__global__ __launch_bounds__(256) void prep_k(const float* __restrict__ x, __half* __restrict__ x16,
                                              const float* __restrict__ W1, const float* __restrict__ W2,
                                              const float* __restrict__ Wmu, const float* __restrict__ Wlv,
                                              __half* __restrict__ W1t, __half* __restrict__ W2t,
                                              __half* __restrict__ Wht,
                                              const int* __restrict__ dst, int* __restrict__ histG,
                                              int e, int nPrep) {
    __shared__ int hist[NB];
    int blk = blockIdx.x;
    int t = threadIdx.x;
    if (blk >= nPrep) {
        int c = blk - nPrep;
        int ch = (e + NCH - 1) / NCH;
        int i0 = c * ch, i1 = i0 + ch; if (i1 > e) i1 = e;
        for (int b = t; b < NB; b += 256) hist[b] = 0;
        __syncthreads();
        for (int i = i0 + t; i < i1; i += 256)
            atomicAdd(&hist[dst[i] >> 7], 1);      // LDS atomics, ~8/counter
        __syncthreads();
        for (int b = t; b < NB; b += 256) histG[c * NB + b] = hist[b];
        return;
    }
    int i = blk * 256 + t;
    const int CAST = N_NODES * IN_DIM / 8;        // 800000
    if (i < CAST) {
        const float4* in4 = (const float4*)x;
        float4 a = in4[2 * i], b = in4[2 * i + 1];
        __half2 h0 = __floats2half2_rn(a.x, a.y);
        __half2 h1 = __floats2half2_rn(a.z, a.w);
        __half2 h2 = __floats2half2_rn(b.x, b.y);
        __half2 h3 = __floats2half2_rn(b.z, b.w);
        uint4 pk = make_uint4(*(unsigned*)&h0, *(unsigned*)&h1, *(unsigned*)&h2, *(unsigned*)&h3);
        ((uint4*)x16)[i] = pk;
        return;
    }
    int j = i - CAST;
    if (j < 128 * 64) {
        int col = j >> 6, k = j & 63;
        W1t[j] = __float2half(W1[k * 128 + col]);
        return;
    }
    int m = j - 128 * 64;
    if (m < 128 * 128) {
        int col = m >> 7, k = m & 127;
        W2t[m] = __float2half(W2[k * 128 + col]);
        return;
    }
    int h = m - 128 * 128;
    if (h < 128 * 128) {
        int col = h >> 7, k = h & 127;
        Wht[h] = __float2half(col < 64 ? Wmu[k * 64 + col] : Wlv[k * 64 + (col - 64)]);
    }
}

// ---------------- CSR build: atomic-free two-pass counting sort ----------------
// Lesson (r1/r8): same-address GLOBAL atomics serialize ~440cy/update regardless of
// return semantics. All global atomics eliminated from the build.

// One WAVE per bucket: prefix over the NCH chunk counts (lane l owns chunks 4l..4l+3,
// wave shfl-scan), written back in place; bucket total -> btot. Replaces the serial
// single-block chunk loop (782-way parallel instead of 1).
__global__ __launch_bounds__(256) void boffB_k(int* __restrict__ histG, int* __restrict__ btot) {
    int wv = (int)((blockIdx.x * 256 + threadIdx.x) >> 6);   // bucket
    if (wv >= NB) return;
    int lane = threadIdx.x & 63;
    int v[4];
#pragma unroll
    for (int k = 0; k < 4; k++) v[k] = histG[(4 * lane + k) * NB + wv];
    int s = v[0] + v[1] + v[2] + v[3];
    int run = s;
#pragma unroll
    for (int off = 1; off < 64; off <<= 1) {
        int tt = __shfl_up(run, off);
        if (lane >= off) run += tt;
    }
    int p = run - s;                                   // exclusive prefix of lane sums
#pragma unroll
    for (int k = 0; k < 4; k++) {
        int tt = v[k];
        histG[(4 * lane + k) * NB + wv] = p;           // chunk-local start within bucket
        p += tt;
    }
    if (lane == 63) btot[wv] = p;                      // bucket total
}

// single-block exclusive scan of NB bucket totals -> ebase
__global__ __launch_bounds__(1024) void bscan_k(const int* __restrict__ btot, int* __restrict__ ebase, int e) {
    __shared__ int s[1024];
    int t = threadIdx.x;
    int v = (t < NB) ? btot[t] : 0;
    s[t] = v;
    __syncthreads();
#pragma unroll
    for (int off = 1; off < 1024; off <<= 1) {
        int x = (t >= off) ? s[t - off] : 0;
        __syncthreads();
        s[t] += x;
        __syncthreads();
    }
    if (t < NB) ebase[t] = s[t] - v;
    if (t == 0) ebase[NB] = e;
}

// Place edges into bucket-contiguous binned[] via LDS cursors seeded from
// ebase[b] + boffs[c][b]. NO global atomics. Packed 4B: {local_dst(7b)<<17 | src(17b)}.
__global__ __launch_bounds__(256) void binB_k(const int* __restrict__ src, const int* __restrict__ dst,
                                              const int* __restrict__ boffs, const int* __restrict__ ebase,
                                              int* __restrict__ binned, int e) {
    __shared__ int cur[NB];
    int c = blockIdx.x, t = threadIdx.x;
    int ch = (e + NCH - 1) / NCH;
    int i0 = c * ch, i1 = i0 + ch; if (i1 > e) i1 = e;
    for (int b = t; b < NB; b += 256) cur[b] = ebase[b] + boffs[c * NB + b];
    __syncthreads();
    for (int i = i0 + t; i < i1; i += 256) {
        int s = src[i], d = dst[i];
        int p = atomicAdd(&cur[d >> 7], 1);    // LDS atomic
        binned[p] = ((d & 127) << 17) | s;
    }
}

// Phase B1: one block per bucket — degrees from binned via LDS hist (+1 self), LDS
// 128-scan -> rowptr (em base = ebase[b] + b*BN), dinv = rsqrt(deg).
__global__ __launch_bounds__(256) void pdeg_k(const int* __restrict__ binned, const int* __restrict__ ebase,
                                              int* __restrict__ rowptr, float* __restrict__ dinv, int n) {
    __shared__ int hist[BN];
    __shared__ int sc[BN];
    int b = blockIdx.x, t = threadIdx.x;
    int n0 = b * BN;
    int nn = n - n0; if (nn > BN) nn = BN;
    if (t < BN) hist[t] = (t < nn) ? 1 : 0;    // self loop
    __syncthreads();
    int e0 = ebase[b], e1 = ebase[b + 1];
    for (int i = e0 + t; i < e1; i += 256)
        atomicAdd(&hist[binned[i] >> 17], 1);
    __syncthreads();
    int v = (t < BN) ? hist[t] : 0;
    if (t < BN) sc[t] = v;
    __syncthreads();
#pragma unroll
    for (int off = 1; off < BN; off <<= 1) {
        int x = (t < BN && t >= off) ? sc[t - off] : 0;
        __syncthreads();
        if (t < BN) sc[t] += x;
        __syncthreads();
    }
    int base = e0 + n0;                        // global em offset of this bucket
    if (t < nn) {
        rowptr[n0 + t] = base + sc[t] - v;     // exclusive
        dinv[n0 + t] = rsqrtf((float)v);
    }
    if (b == gridDim.x - 1 && t == 0) rowptr[n] = E_TOT;
}

// Phase B2: fill em (dinv globally complete). Self first, then edges via LDS cursors;
// all writes for the bucket's ~14KB region come from ONE CU -> line-merged in its L2.
__global__ __launch_bounds__(256) void pfill_k(const int* __restrict__ binned, const int* __restrict__ ebase,
                                               const int* __restrict__ rowptr, const float* __restrict__ dinv,
                                               int2* __restrict__ em, int n) {
    __shared__ int cur[BN];
    __shared__ float sdv[BN];
    int b = blockIdx.x, t = threadIdx.x;
    int n0 = b * BN;
    int nn = n - n0; if (nn > BN) nn = BN;
    if (t < nn) {
        int rp = rowptr[n0 + t];
        float dv = dinv[n0 + t];
        sdv[t] = dv;
        em[rp] = make_int2(n0 + t, __float_as_int(dv * dv));   // self loop first
        cur[t] = rp + 1;
    }
    __syncthreads();
    int e0 = ebase[b], e1 = ebase[b + 1];
    for (int i = e0 + t; i < e1; i += 256) {
        int pk = binned[i];
        int ld = pk >> 17, s = pk & 0x1FFFF;
        int q = atomicAdd(&cur[ld], 1);
        em[q] = make_int2(s, __float_as_int(dinv[s] * sdv[ld]));
    }
}

// ---------------- Aggregation (gather): fp16 rows, fp32 accumulate ----------------
// One node per wave; granule = 2 slots (STEP edges). 4-phase rotated software pipeline:
// body(p) issues rows(g+2), FMAs granule g, fetches meta(g+4). Prefetches past end are
// clamp-indexed to beg with weight 0 (branch-free). [round-6 structure, measured ~65us]

template <int DIM, bool HEAD>
__global__ __launch_bounds__(256) void agg_k(const __half* __restrict__ H, const int* __restrict__ rowptr,
                                             const int2* __restrict__ em, __half* __restrict__ out,
                                             const float* __restrict__ bmu, const float* __restrict__ blv,
                                             float* __restrict__ mu, float* __restrict__ lv, int n) {
    int node = (int)((blockIdx.x * 256 + threadIdx.x) >> 6);
    if (node >= n) return;
    int lane = threadIdx.x & 63;
    int beg = rowptr[node], end = rowptr[node + 1];
    const uint4* H4 = (const uint4*)H;

    constexpr int RV   = DIM / 8;            // 16B-chunks per row (128->16, 64->8)
    constexpr int SUBS = 64 / RV;            // parallel edge slots (4 or 8)
    constexpr int STEP = SUBS * 2;           // edges per granule (8 or 16)
    int sub = lane / RV;
    int fl  = lane % RV;

    float acc[8];
#pragma unroll
    for (int q = 0; q < 8; q++) acc[q] = 0.f;

    auto meta = [&](int j, int p, int& s, float& w) {
        int idx = j + SUBS * p + sub;
        int ci  = idx < end ? idx : beg;
        int2 e  = em[ci];
        s = e.x;
        w = idx < end ? __int_as_float(e.y) : 0.f;
    };
    auto rows = [&](int s0, int s1, uint4& r0, uint4& r1) {
        r0 = H4[(size_t)s0 * RV + fl];
        r1 = H4[(size_t)s1 * RV + fl];
    };
    auto fmas = [&](const uint4& r0, const uint4& r1, float ww0, float ww1) {
        const __half* h0 = (const __half*)&r0;
        const __half* h1 = (const __half*)&r1;
#pragma unroll
        for (int q = 0; q < 8; q++) acc[q] = fmaf(ww0, __half2float(h0[q]), acc[q]);
#pragma unroll
        for (int q = 0; q < 8; q++) acc[q] = fmaf(ww1, __half2float(h1[q]), acc[q]);
    };

    int G = (end - beg + STEP - 1) / STEP;   // granules (>=1: self loop)

    int   sa0, sa1, sb0, sb1, sc0, sc1, sd0, sd1;
    float wa0, wa1, wb0, wb1, wc0, wc1, wd0, wd1;
    uint4 ra0, ra1, rb0, rb1, rc0, rc1, rd0, rd1;

    // prologue: meta g0..g3, rows g0,g1
    meta(beg,            0, sa0, wa0); meta(beg,            1, sa1, wa1);
    meta(beg + STEP,     0, sb0, wb0); meta(beg + STEP,     1, sb1, wb1);
    rows(sa0, sa1, ra0, ra1);
    rows(sb0, sb1, rb0, rb1);
    meta(beg + 2 * STEP, 0, sc0, wc0); meta(beg + 2 * STEP, 1, sc1, wc1);
    meta(beg + 3 * STEP, 0, sd0, wd0); meta(beg + 3 * STEP, 1, sd1, wd1);

    int g = 0;
    int jf = beg + 4 * STEP;                 // next meta granule start to fetch
    while (true) {
        rows(sc0, sc1, rc0, rc1);            // issue g+2
        fmas(ra0, ra1, wa0, wa1);            // consume g
        if (++g >= G) break;
        meta(jf, 0, sa0, wa0); meta(jf, 1, sa1, wa1); jf += STEP;   // fetch g+4

        rows(sd0, sd1, rd0, rd1);
        fmas(rb0, rb1, wb0, wb1);
        if (++g >= G) break;
        meta(jf, 0, sb0, wb0); meta(jf, 1, sb1, wb1); jf += STEP;

        rows(sa0, sa1, ra0, ra1);
        fmas(rc0, rc1, wc0, wc1);
        if (++g >= G) break;
        meta(jf, 0, sc0, wc0); meta(jf, 1, sc1, wc1); jf += STEP;

        rows(sb0, sb1, rb0, rb1);
        fmas(rd0, rd1, wd0, wd1);
        if (++g >= G) break;
        meta(jf, 0, sd0, wd0); meta(jf, 1, sd1, wd1); jf += STEP;
    }

    // combine sub-groups: xor-reduce down to sub==0
#pragma unroll
    for (int off = 32; off >= RV; off >>= 1) {
#pragma unroll
        for (int q = 0; q < 8; q++) acc[q] += __shfl_xor(acc[q], off);
    }
    if (sub == 0) {
        if constexpr (HEAD) {
            // feats fl*8 .. fl*8+7; fl<8 -> mu, fl>=8 -> logvar (chunks don't straddle 64)
            const float* bp = (fl < 8) ? (bmu + fl * 8) : (blv + (fl - 8) * 8);
#pragma unroll
            for (int q = 0; q < 8; q++) acc[q] += bp[q];
            float* op = (fl < 8) ? (mu + (size_t)node * 64 + fl * 8)
                                 : (lv + (size_t)node * 64 + (fl - 8) * 8);
            *(float4*)op = make_float4(acc[0], acc[1], acc[2], acc[3]);
            *(float4*)(op + 4) = make_float4(acc[4], acc[5], acc[6], acc[7]);
        } else {
            __half2 q0 = __floats2half2_rn(acc[0], acc[1]);
            __half2 q1 = __floats2half2_rn(acc[2], acc[3]);
            __half2 q2 = __floats2half2_rn(acc[4], acc[5]);
            __half2 q3 = __floats2half2_rn(acc[6], acc[7]);
            uint4 pk = make_uint4(*(unsigned*)&q0, *(unsigned*)&q1, *(unsigned*)&q2, *(unsigned*)&q3);
            *(uint4*)(out + (size_t)node * DIM + fl * 8) = pk;
        }
    }
}

// ---------------- MFMA GEMM: C[n x 128] = A[n x K] @ W[K x 128] (+bias, relu) ----------
// 256 thr = 4 waves, 64 rows/block (wave w -> rows m0+16w..+15), 8 col-tiles per wave.
// W^T fp16 staged in LDS ([col][k], 16/32 KB) with XOR swizzle ^((col&7)<<4) to kill the
// 16-way ds_read_b128 bank conflict. A fragments loaded direct from global (16B/lane).
// mfma_f32_16x16x32_f16: a[e]=A[lane&15][(lane>>4)*8+e], b[e]=W[(lane>>4)*8+e][col],
// d[r]=C[(lane>>4)*4+r][col=lane&15] (per verified gfx950 layout).

template <int K, bool BR>
__global__ __launch_bounds__(256) void mgemm_k(const __half* __restrict__ A,
                                               const __half* __restrict__ Wt,   // [128][K] fp16
                                               const float* __restrict__ bias,
                                               __half* __restrict__ C, int n) {
    __shared__ __align__(16) __half Wl[128 * K];
    int t = threadIdx.x;

    // stage Wt -> LDS (16B chunks, XOR swizzle on write; reads use the same XOR)
    constexpr int CHUNKS = 128 * K / 8;     // 16B chunks
    const uint4* Wg = (const uint4*)Wt;
    for (int i = t; i < CHUNKS; i += 256) {
        int g = i * 16;
        int col = g / (2 * K);
        uint4 v = Wg[i];
        *(uint4*)((char*)Wl + (g ^ ((col & 7) << 4))) = v;
    }
    __syncthreads();

    int lane = t & 63, w = t >> 6;
    int colb = lane & 15;
    int kq = (lane >> 4) * 8;
    int m0 = blockIdx.x * 64 + w * 16;
    int rowA = m0 + colb; if (rowA >= n) rowA = n - 1;
    const __half* Arow = A + (size_t)rowA * K + kq;

    f32x4 acc[8];
#pragma unroll
    for (int c = 0; c < 8; c++) acc[c] = (f32x4){0.f, 0.f, 0.f, 0.f};

    const char* wb = (const char*)Wl;
    int swz = (colb & 7) << 4;
    int off0 = colb * (2 * K) + kq * 2;

#pragma unroll
    for (int k0 = 0; k0 < K; k0 += 32) {
        f16x8 a = *(const f16x8*)(Arow + k0);
#pragma unroll
        for (int c = 0; c < 8; c++) {
            f16x8 b = *(const f16x8*)(wb + ((off0 + c * (32 * K) + k0 * 2) ^ swz));
            acc[c] = __builtin_amdgcn_mfma_f32_16x16x32_f16(a, b, acc[c], 0, 0, 0);
        }
    }

    int rbase = m0 + (lane >> 4) * 4;
#pragma unroll
    for (int c = 0; c < 8; c++) {
        int col = c * 16 + colb;
        float bv = BR ? bias[col] : 0.f;
#pragma unroll
        for (int r = 0; r < 4; r++) {
            int row = rbase + r;
            if (row < n) {
                float v = acc[c][r] + bv;
                if (BR) v = fmaxf(v, 0.f);
                C[(size_t)row * 128 + col] = __float2half(v);
            }
        }
    }
}

// ---------------- launch ----------------

extern "C" void kernel_launch(void* const* d_in, const int* in_sizes, int n_in,
                              void* d_out, int out_size, void* d_ws, size_t ws_size,
                              hipStream_t stream) {
    const int N = N_NODES, E = N_EDGES, ETOT = E_TOT;

    const float* x    = (const float*)d_in[0];
    const int*   ei   = (const int*)d_in[1];
    const int*   srcA = ei;
    const int*   dstA = ei + E;
    const float* W1   = (const float*)d_in[2];
    const float* b1   = (const float*)d_in[3];
    const float* W2   = (const float*)d_in[4];
    const float* b2   = (const float*)d_in[5];
    const float* Wmu  = (const float*)d_in[6];
    const float* bmu  = (const float*)d_in[7];
    const float* Wlv  = (const float*)d_in[8];
    const float* blv  = (const float*)d_in[9];
    float* out = (float*)d_out;

    // workspace carve-out
    char* ws = (char*)d_ws;
    size_t o = 0;
    auto alloc = [&](size_t bytes) -> void* {
        o = (o + 255) & ~(size_t)255;
        void* p = ws + o;
        o += bytes;
        return p;
    };
    int*    histG  = (int*)alloc((size_t)NCH * NB * 4);       // counts -> boffs (in place)
    int*    btot   = (int*)alloc((size_t)NB * 4);
    int*    ebase  = (int*)alloc((size_t)(NB + 1) * 4);
    int*    rowptr = (int*)alloc((size_t)(N + 1) * 4);
    float*  dinv   = (float*)alloc((size_t)N * 4);
    int2*   em     = (int2*)alloc((size_t)ETOT * 8);          // packed {src, norm}
    int*    binned = (int*)alloc((size_t)E * 4);
    __half* x16    = (__half*)alloc((size_t)N * IN_DIM * 2);
    __half* B1     = (__half*)alloc((size_t)N * HIDDEN * 2);  // agg out / P
    __half* B2     = (__half*)alloc((size_t)N * HIDDEN * 2);  // gemm out
    __half* W1t    = (__half*)alloc(128 * 64 * 2);
    __half* W2t    = (__half*)alloc(128 * 128 * 2);
    __half* Wht    = (__half*)alloc(128 * 128 * 2);
    (void)ws_size;

    const int PREP_T = N * IN_DIM / 8 + 128 * 64 + 128 * 128 + 128 * 128;
    const int nPrep = (PREP_T + 255) / 256;
    const int gAgg = (N + 3) / 4;            // 25000 (4 nodes/block)
    const int gMg  = (N + 63) / 64;          // 1563 (64 rows/block)
    const int gBoff = (NB * 64 + 255) / 256; // 196 blocks (1 wave/bucket)

    // CSR build, fully atomic-free at global scope:
    // prep(+chunk-hist) -> wave-per-bucket chunk-prefix -> tiny bucket scan ->
    // chunk-place -> bucket-local degree+scan -> bucket-local fill.
    prep_k<<<nPrep + NCH, 256, 0, stream>>>(x, x16, W1, W2, Wmu, Wlv, W1t, W2t, Wht,
                                            dstA, histG, E, nPrep);
    boffB_k<<<gBoff, 256, 0, stream>>>(histG, btot);
    bscan_k<<<1, 1024, 0, stream>>>(btot, ebase, E);
    binB_k<<<NCH, 256, 0, stream>>>(srcA, dstA, histG, ebase, binned, E);
    pdeg_k<<<NB, 256, 0, stream>>>(binned, ebase, rowptr, dinv, N);
    pfill_k<<<NB, 256, 0, stream>>>(binned, ebase, rowptr, dinv, em, N);

    // layer 1: h = relu(Agg(x16) @ W1 + b1)        [agg 64-dim -> MFMA K=64]
    agg_k<64, false><<<gAgg, 256, 0, stream>>>(x16, rowptr, em, B1, nullptr, nullptr, nullptr, nullptr, N);
    mgemm_k<64, true><<<gMg, 256, 0, stream>>>(B1, W1t, b1, B2, N);

    // layer 2: h = relu(Agg(h) @ W2 + b2)          [agg 128-dim -> MFMA K=128]
    agg_k<128, false><<<gAgg, 256, 0, stream>>>(B2, rowptr, em, B1, nullptr, nullptr, nullptr, nullptr, N);
    mgemm_k<128, true><<<gMg, 256, 0, stream>>>(B1, W2t, b2, B2, N);

    // heads via linearity: P = h @ [Wmu|Wlv] (fp16), then out = Agg(P) + bias (fp32)
    mgemm_k<128, false><<<gMg, 256, 0, stream>>>(B2, Wht, nullptr, B1, N);
    agg_k<128, true><<<gAgg, 256, 0, stream>>>(B1, rowptr, em, nullptr, bmu, blv,
                                               out, out + (size_t)N * Z_DIM, N);
}